// Round 3
// baseline (217.630 us; speedup 1.0000x reference)
//
#include <hip/hip_runtime.h>
#include <math.h>

// VectorQuantizer: B=4, T=2048, DIM=64, NUM_CODES=512
// out = [ k as float (8192) | z_q (8192*64) ]
//
// Register-tiled distance kernel: each lane computes a 4-query x 4-code tile,
// both operands from XOR-swizzled LDS tiles. Summation per pair uses the
// bit-exact round-0 order: acc[d&7] accumulated in ascending dim order +
// fixed combine tree, then sqrtf, then strict-< ascending-index argmin.

#define NQ      8192
#define VDIM    64
#define NCODES  512
#define QB      64                  // queries per block
#define CB      64                  // codes per block
#define NCHUNK  (NCODES / CB)       // 8

__global__ __launch_bounds__(256, 2) void vq_dist_kernel(
    const float* __restrict__ inp,     // [NQ][VDIM]
    const float* __restrict__ table,   // [NCODES][VDIM]
    float* __restrict__ wnorm,         // [NCHUNK][NQ]
    int* __restrict__ widx)            // [NCHUNK][NQ]
{
    __shared__ float qt[QB * VDIM];    // swizzled: row q, 16B-col (kc ^ (q&15))
    __shared__ float ct[CB * VDIM];
    __shared__ float rn[4][QB];        // cross-wave reduce: norms
    __shared__ int   ri[4][QB];        // cross-wave reduce: indices

    const int tid = threadIdx.x;
    const int bq  = blockIdx.x / NCHUNK;   // 0..127 query block
    const int bc  = blockIdx.x % NCHUNK;   // 0..7   code chunk (fast: q-tile L2 reuse)

    // ---- Stage q-tile and c-tile into LDS, XOR-swizzled in 16B units ----
    {
        const float4* gq = reinterpret_cast<const float4*>(inp   + (size_t)bq * QB * VDIM);
        const float4* gc = reinterpret_cast<const float4*>(table + (size_t)bc * CB * VDIM);
        float4* qdst = reinterpret_cast<float4*>(qt);
        float4* cdst = reinterpret_cast<float4*>(ct);
#pragma unroll
        for (int i = 0; i < 4; ++i) {
            int f  = tid + i * 256;        // flat float4 index, 0..1023
            int r  = f >> 4;               // row
            int kc = f & 15;               // 16B column (4 dims)
            qdst[r * 16 + (kc ^ (r & 15))] = gq[f];
            cdst[r * 16 + (kc ^ (r & 15))] = gc[f];
        }
    }
    __syncthreads();

    const int qg = tid & 15;           // query group: queries qg*4 .. qg*4+3
    const int cg = tid >> 4;           // code group:  codes  cg*4 .. cg*4+3

    const float4* qt4 = reinterpret_cast<const float4*>(qt);
    const float4* ct4 = reinterpret_cast<const float4*>(ct);

    // acc[i][j][m]: m = d&7 accumulator, exact round-0 grouping/order
    float acc[4][4][8];
#pragma unroll
    for (int i = 0; i < 4; ++i)
#pragma unroll
        for (int j = 0; j < 4; ++j)
#pragma unroll
            for (int m = 0; m < 8; ++m) acc[i][j][m] = 0.0f;

#pragma unroll
    for (int kc = 0; kc < 16; ++kc) {  // dims kc*4 .. kc*4+3
        float4 qv[4], cv[4];
#pragma unroll
        for (int i = 0; i < 4; ++i) {
            int q = qg * 4 + i;
            qv[i] = qt4[q * 16 + (kc ^ (q & 15))];
            int c = cg * 4 + i;
            cv[i] = ct4[c * 16 + (kc ^ (c & 15))];
        }
        const int mb = (kc & 1) * 4;   // dims kc*4+m have (d&7) == mb+m
#pragma unroll
        for (int i = 0; i < 4; ++i) {
#pragma unroll
            for (int j = 0; j < 4; ++j) {
                float d0 = qv[i].x - cv[j].x;
                float d1 = qv[i].y - cv[j].y;
                float d2 = qv[i].z - cv[j].z;
                float d3 = qv[i].w - cv[j].w;
                acc[i][j][mb + 0] = __builtin_fmaf(d0, d0, acc[i][j][mb + 0]);
                acc[i][j][mb + 1] = __builtin_fmaf(d1, d1, acc[i][j][mb + 1]);
                acc[i][j][mb + 2] = __builtin_fmaf(d2, d2, acc[i][j][mb + 2]);
                acc[i][j][mb + 3] = __builtin_fmaf(d3, d3, acc[i][j][mb + 3]);
            }
        }
    }

    // ---- Per-lane: combine tree (round-0 exact), sqrt, argmin over 4 codes ----
    float bd[4];
    int   bi[4];
#pragma unroll
    for (int i = 0; i < 4; ++i) { bd[i] = INFINITY; bi[i] = 0; }
#pragma unroll
    for (int j = 0; j < 4; ++j) {          // ascending code index
#pragma unroll
        for (int i = 0; i < 4; ++i) {
            float s = ((acc[i][j][0] + acc[i][j][1]) + (acc[i][j][2] + acc[i][j][3]))
                    + ((acc[i][j][4] + acc[i][j][5]) + (acc[i][j][6] + acc[i][j][7]));
            float n = sqrtf(s);
            if (n < bd[i]) { bd[i] = n; bi[i] = bc * CB + cg * 4 + j; }
        }
    }

    // ---- Intra-wave reduce across the 4 code-groups sharing this qg ----
#pragma unroll
    for (int off = 16; off < 64; off <<= 1) {
#pragma unroll
        for (int i = 0; i < 4; ++i) {
            float nd = __shfl_xor(bd[i], off, 64);
            int   ni = __shfl_xor(bi[i], off, 64);
            if (nd < bd[i] || (nd == bd[i] && ni < bi[i])) { bd[i] = nd; bi[i] = ni; }
        }
    }

    // ---- Cross-wave reduce via LDS (each wave covers 16 codes, all 64 queries) ----
    if (((tid >> 4) & 3) == 0) {           // one code-group rep per wave
        int w = tid >> 6;
#pragma unroll
        for (int i = 0; i < 4; ++i) {
            rn[w][qg * 4 + i] = bd[i];
            ri[w][qg * 4 + i] = bi[i];
        }
    }
    __syncthreads();

    if (tid < QB) {
        float n = INFINITY;
        int   idx = 0;
#pragma unroll
        for (int w = 0; w < 4; ++w) {      // ascending code ranges
            float nn = rn[w][tid];
            int   ni = ri[w][tid];
            if (nn < n || (nn == n && ni < idx)) { n = nn; idx = ni; }
        }
        wnorm[(size_t)bc * NQ + bq * QB + tid] = n;
        widx [(size_t)bc * NQ + bq * QB + tid] = idx;
    }
}

// Reduce the 8 chunk-partials per query, write k (as float) and gather z_q.
__global__ __launch_bounds__(256) void vq_finalize_kernel(
    const float* __restrict__ table,
    const float* __restrict__ wnorm,
    const int* __restrict__ widx,
    float* __restrict__ out)
{
    const int gid = blockIdx.x * 256 + threadIdx.x;   // 0 .. NQ*64
    const int q = gid >> 6;
    const int d = gid & 63;

    float best = INFINITY;
    int   bidx = 0;
#pragma unroll
    for (int p = 0; p < NCHUNK; ++p) {
        float n = wnorm[(size_t)p * NQ + q];
        int   i = widx [(size_t)p * NQ + q];
        if (n < best || (n == best && i < bidx)) { best = n; bidx = i; }
    }

    out[NQ + (size_t)q * VDIM + d] = table[(size_t)bidx * VDIM + d];
    if (d == 0) out[q] = (float)bidx;
}

extern "C" void kernel_launch(void* const* d_in, const int* in_sizes, int n_in,
                              void* d_out, int out_size, void* d_ws, size_t ws_size,
                              hipStream_t stream) {
    const float* inp   = (const float*)d_in[0];   // [4,2048,64] fp32
    const float* table = (const float*)d_in[1];   // [512,64]    fp32
    float* out = (float*)d_out;

    float* wnorm = (float*)d_ws;                        // NCHUNK*NQ floats (256 KB)
    int*   widx  = (int*)(wnorm + (size_t)NCHUNK * NQ); // NCHUNK*NQ ints   (256 KB)

    vq_dist_kernel<<<dim3((NQ / QB) * NCHUNK), dim3(256), 0, stream>>>(inp, table, wnorm, widx);
    vq_finalize_kernel<<<dim3((NQ * VDIM) / 256), dim3(256), 0, stream>>>(table, wnorm, widx, out);
}

// Round 4
// 36.830 us; speedup vs baseline: 5.9090x; 5.9090x over previous
//
#include <hip/hip_runtime.h>
#include <math.h>

// VectorQuantizer: B=4, T=2048, DIM=64, NUM_CODES=512
// out = [ k as float (8192) | z_q (8192*64) ]
//
// R3: register-tiled 4q x 4c per lane, 1-wave blocks (32q x 32c), spill-free
// (acc 128 + operands ~64 + misc < 256 VGPR cap at 2 waves/SIMD).
// Distance math bit-matches the validated R0/R2 path: acc[d&7] ascending-dim
// accumulation, fixed combine tree, IEEE sqrtf, strict-< ascending argmin.

#define NQ      8192
#define VDIM    64
#define NCODES  512
#define QB      32
#define CB      32
#define NCHUNK  (NCODES / CB)        // 16

__global__ __launch_bounds__(64, 2) void vq_dist_kernel(
    const float* __restrict__ inp,     // [NQ][VDIM]
    const float* __restrict__ table,   // [NCODES][VDIM]
    float* __restrict__ wnorm,         // [NCHUNK][NQ]
    int* __restrict__ widx)            // [NCHUNK][NQ]
{
    __shared__ float4 qt[QB * 16];     // 8 KB, row r at col (kc ^ ((r>>2)&7))
    __shared__ float4 ct[CB * 16];     // 8 KB

    const int l  = threadIdx.x;                // 0..63
    const int bc = blockIdx.x & (NCHUNK - 1);  // code chunk (fast dim)
    const int bq = blockIdx.x >> 4;            // query block

    // ---- Stage tiles (coalesced global f4 reads, swizzled LDS writes) ----
    {
        const float4* gq = reinterpret_cast<const float4*>(inp   + (size_t)bq * QB * VDIM);
        const float4* gc = reinterpret_cast<const float4*>(table + (size_t)bc * CB * VDIM);
#pragma unroll
        for (int it = 0; it < 8; ++it) {
            int f  = l + it * 64;              // 0..511
            int r  = f >> 4;
            int kc = f & 15;
            int d  = r * 16 + (kc ^ ((r >> 2) & 7));
            qt[d] = gq[f];
            ct[d] = gc[f];
        }
    }
    __syncthreads();

    const int xq = l & 7;              // q-group: rows 4*xq .. 4*xq+3
    const int xc = l >> 3;             // c-group: rows 4*xc .. 4*xc+3
    const float4* qb = qt + xq * 4 * 16;
    const float4* cb = ct + xc * 4 * 16;

    // acc[i][j][m]: m = (dim & 7), exact round-0 grouping/order
    float acc[4][4][8];
#pragma unroll
    for (int i = 0; i < 4; ++i)
#pragma unroll
        for (int j = 0; j < 4; ++j)
#pragma unroll
            for (int m = 0; m < 8; ++m) acc[i][j][m] = 0.0f;

#pragma clang loop unroll(disable)
    for (int k = 0; k < 8; ++k) {
        // ---- kstep even: kc = 2k, dims 8k..8k+3 -> acc[0..3] ----
        {
            const int kc = 2 * k;
            float4 qv[4], cv[4];
#pragma unroll
            for (int i = 0; i < 4; ++i) qv[i] = qb[i * 16 + (kc ^ xq)];
#pragma unroll
            for (int j = 0; j < 4; ++j) cv[j] = cb[j * 16 + (kc ^ xc)];
#pragma unroll
            for (int i = 0; i < 4; ++i)
#pragma unroll
                for (int j = 0; j < 4; ++j) {
                    float d0 = qv[i].x - cv[j].x;
                    float d1 = qv[i].y - cv[j].y;
                    float d2 = qv[i].z - cv[j].z;
                    float d3 = qv[i].w - cv[j].w;
                    acc[i][j][0] = __builtin_fmaf(d0, d0, acc[i][j][0]);
                    acc[i][j][1] = __builtin_fmaf(d1, d1, acc[i][j][1]);
                    acc[i][j][2] = __builtin_fmaf(d2, d2, acc[i][j][2]);
                    acc[i][j][3] = __builtin_fmaf(d3, d3, acc[i][j][3]);
                }
        }
        // ---- kstep odd: kc = 2k+1, dims 8k+4..8k+7 -> acc[4..7] ----
        {
            const int kc = 2 * k + 1;
            float4 qv[4], cv[4];
#pragma unroll
            for (int i = 0; i < 4; ++i) qv[i] = qb[i * 16 + (kc ^ xq)];
#pragma unroll
            for (int j = 0; j < 4; ++j) cv[j] = cb[j * 16 + (kc ^ xc)];
#pragma unroll
            for (int i = 0; i < 4; ++i)
#pragma unroll
                for (int j = 0; j < 4; ++j) {
                    float d0 = qv[i].x - cv[j].x;
                    float d1 = qv[i].y - cv[j].y;
                    float d2 = qv[i].z - cv[j].z;
                    float d3 = qv[i].w - cv[j].w;
                    acc[i][j][4] = __builtin_fmaf(d0, d0, acc[i][j][4]);
                    acc[i][j][5] = __builtin_fmaf(d1, d1, acc[i][j][5]);
                    acc[i][j][6] = __builtin_fmaf(d2, d2, acc[i][j][6]);
                    acc[i][j][7] = __builtin_fmaf(d3, d3, acc[i][j][7]);
                }
        }
    }

    // ---- Combine tree (round-0 exact), sqrt, per-lane argmin over 4 codes ----
    float bd[4];
    int   bi[4];
#pragma unroll
    for (int i = 0; i < 4; ++i) { bd[i] = INFINITY; bi[i] = 0; }
#pragma unroll
    for (int j = 0; j < 4; ++j) {          // ascending code index
#pragma unroll
        for (int i = 0; i < 4; ++i) {
            float s = ((acc[i][j][0] + acc[i][j][1]) + (acc[i][j][2] + acc[i][j][3]))
                    + ((acc[i][j][4] + acc[i][j][5]) + (acc[i][j][6] + acc[i][j][7]));
            float n = sqrtf(s);
            if (n < bd[i]) { bd[i] = n; bi[i] = bc * CB + xc * 4 + j; }
        }
    }

    // ---- Reduce across the 8 c-groups (lanes l^8, l^16, l^32) ----
#pragma unroll
    for (int off = 8; off < 64; off <<= 1) {
#pragma unroll
        for (int i = 0; i < 4; ++i) {
            float nd = __shfl_xor(bd[i], off, 64);
            int   ni = __shfl_xor(bi[i], off, 64);
            if (nd < bd[i] || (nd == bd[i] && ni < bi[i])) { bd[i] = nd; bi[i] = ni; }
        }
    }

    if (xc == 0) {                         // lanes 0..7, one per q-group
#pragma unroll
        for (int i = 0; i < 4; ++i) {
            wnorm[(size_t)bc * NQ + bq * QB + 4 * l + i] = bd[i];
            widx [(size_t)bc * NQ + bq * QB + 4 * l + i] = bi[i];
        }
    }
}

// Reduce the 16 chunk-partials per query, write k (as float) and gather z_q.
__global__ __launch_bounds__(256) void vq_finalize_kernel(
    const float* __restrict__ table,
    const float* __restrict__ wnorm,
    const int* __restrict__ widx,
    float* __restrict__ out)
{
    const int gid = blockIdx.x * 256 + threadIdx.x;   // 0 .. NQ*64
    const int q = gid >> 6;
    const int d = gid & 63;

    float best = INFINITY;
    int   bidx = 0;
#pragma unroll
    for (int p = 0; p < NCHUNK; ++p) {
        float n = wnorm[(size_t)p * NQ + q];
        int   i = widx [(size_t)p * NQ + q];
        if (n < best || (n == best && i < bidx)) { best = n; bidx = i; }
    }

    out[NQ + (size_t)q * VDIM + d] = table[(size_t)bidx * VDIM + d];
    if (d == 0) out[q] = (float)bidx;
}

extern "C" void kernel_launch(void* const* d_in, const int* in_sizes, int n_in,
                              void* d_out, int out_size, void* d_ws, size_t ws_size,
                              hipStream_t stream) {
    const float* inp   = (const float*)d_in[0];   // [4,2048,64] fp32
    const float* table = (const float*)d_in[1];   // [512,64]    fp32
    float* out = (float*)d_out;

    float* wnorm = (float*)d_ws;                        // NCHUNK*NQ floats (512 KB)
    int*   widx  = (int*)(wnorm + (size_t)NCHUNK * NQ); // NCHUNK*NQ ints   (512 KB)

    vq_dist_kernel<<<dim3((NQ / QB) * NCHUNK), dim3(64), 0, stream>>>(inp, table, wnorm, widx);
    vq_finalize_kernel<<<dim3((NQ * VDIM) / 256), dim3(256), 0, stream>>>(table, wnorm, widx, out);
}